// Round 6
// baseline (2290.860 us; speedup 1.0000x reference)
//
#include <hip/hip_runtime.h>

// Problem constants
#define T_STEPS 512
#define BATCH   256
#define DIN     128
#define DH      512
#define DOUT    128
#define RGRP    16         // rowgroups (BATCH/16), one block each

typedef __attribute__((ext_vector_type(8))) short  short8;   // 8 bf16 (4 VGPRs)
typedef __attribute__((ext_vector_type(4))) float  floatx4;  // MFMA acc

union Pack8 { short8 s; unsigned short h[8]; };
union Pack4 { unsigned long long u; unsigned short h[4]; };

__device__ __forceinline__ float bf2f(unsigned short u) {
    union { unsigned int i; float f; } v; v.i = ((unsigned int)u) << 16; return v.f;
}
// round-half-up: max err 0.5 ulp (tie bias negligible vs 4x error margin)
__device__ __forceinline__ unsigned short f2bf(float f) {
    union { float f; unsigned int i; } v; v.f = f;
    return (unsigned short)((v.i + 0x8000u) >> 16);
}
__device__ __forceinline__ float fast_tanh(float v) {
    float ex = __expf(v + v);
    return 1.f - 2.f / (ex + 1.f);
}

// ---------------------------------------------------------------------------
// Pack row-major fp32 [K][N] into bf16 B-fragment order:
//   Wp[ntile][kc][lane][8], lane = quad*16 + (n&15), j = k&7.
// ---------------------------------------------------------------------------
__global__ void pack_b_kernel(const float* __restrict__ W,
                              unsigned short* __restrict__ Wp, int K, int N) {
    int idx = blockIdx.x * blockDim.x + threadIdx.x;
    if (idx >= K * N) return;
    int k = idx / N, n = idx % N;
    int nt = n >> 4, kc = k >> 5, quad = (k >> 3) & 3, j = k & 7;
    int lane = quad * 16 + (n & 15);
    int KC = K >> 5;
    Wp[((size_t)(nt * KC + kc) * 64 + lane) * 8 + j] = f2bf(W[idx]);
}

// xp2 layout: u64 element index [(t*16+rg)*4 + w][i(0..7)][lane] -> 4 bf16
// (rows q*4+r, col (8w+i)*16+m) — exactly the rnn epilogue's lane ownership.
__device__ __forceinline__ size_t xpidx(int tb_blk, int w, int i, int lane) {
    return (((size_t)tb_blk * 4 + w) * 8 + i) * 64 + lane;
}

// ---------------------------------------------------------------------------
// xproj: xp[tb][n] = sum_k xs[tb][k] * W1x[k][n], stored bf16 in the
// pre-swizzled xp2 layout above (coalesced b64 per lane).
// ---------------------------------------------------------------------------
__global__ __launch_bounds__(256) void xproj_kernel(
        const float* __restrict__ xs,
        const unsigned short* __restrict__ W1xp,
        unsigned long long* __restrict__ xq) {
    const int tid  = threadIdx.x;
    const int lane = tid & 63;
    const int w    = tid >> 6;
    const int m    = lane & 15;
    const int q    = lane >> 4;
    const long row0 = (long)blockIdx.x * 16;

    short8 a[4];
#pragma unroll
    for (int kc = 0; kc < 4; ++kc) {
        const float* src = xs + (row0 + m) * DIN + kc * 32 + q * 8;
        Pack8 av;
#pragma unroll
        for (int j = 0; j < 8; ++j) av.h[j] = f2bf(src[j]);
        a[kc] = av.s;
    }

#pragma unroll
    for (int i = 0; i < 8; ++i) {
        const int nt = w * 8 + i;
        floatx4 acc = {0.f, 0.f, 0.f, 0.f};
#pragma unroll
        for (int kc = 0; kc < 4; ++kc) {
            short8 b = *(const short8*)(W1xp + ((size_t)(nt * 4 + kc) * 64 + lane) * 8);
            acc = __builtin_amdgcn_mfma_f32_16x16x32_bf16(a[kc], b, acc, 0, 0, 0);
        }
        Pack4 pk;
#pragma unroll
        for (int r = 0; r < 4; ++r) pk.h[r] = f2bf(acc[r]);
        xq[xpidx(blockIdx.x, w, i, lane)] = pk.u;
    }
}

// ---------------------------------------------------------------------------
// Recurrence: 16 blocks x 256 threads (4 waves, 1 wave/SIMD -> 512-reg/lane
// budget). Wave w owns ntiles 8w..8w+7 (128 cols). W1h split:
//   kc 0..9   -> registers (bfr: 10 kc x 8 nt = 320 VGPRs/lane)
//   kc 10..10+LKC-1 -> LDS (Wl, written once)
//   rest      -> streamed from L2 per step (consume sb, then reload for next kc)
// Hb double-buffered [2][16][516]: +4 pad -> A-reads 2-way-free (free),
// epilogue scatter writes conflict-free. 1 barrier/step, block-local only.
// ---------------------------------------------------------------------------
template <int LKC>
__global__ __launch_bounds__(256, 1) void rnn_kernel(
        const unsigned long long* __restrict__ xq,
        const unsigned short* __restrict__ W1hp,
        const float* __restrict__ b1p,
        const unsigned short* __restrict__ W2p,
        const float* __restrict__ b2p,
        float* __restrict__ out) {
    extern __shared__ unsigned short smem[];
    unsigned short* Hb = smem;                 // [2][16][516]
    unsigned short* Wl = smem + 2 * 16 * 516;  // [LKC][32 nt][64 lane][8]
#define HROW 516
#define HBUF 8256

    const int tid  = threadIdx.x;
    const int lane = tid & 63;
    const int w    = tid >> 6;      // 0..3
    const int m    = lane & 15;
    const int q    = lane >> 4;
    const int rg   = blockIdx.x;
    const float b1 = b1p[0];
    constexpr int RKC  = 10;        // register-resident kc count
    constexpr int SKC0 = RKC + LKC; // first streamed kc

    // ---- register-resident W1h: wave's 8 ntiles x kc 0..9 ----
    short8 bfr[RKC][8];
#pragma unroll
    for (int kc = 0; kc < RKC; ++kc)
#pragma unroll
        for (int i = 0; i < 8; ++i)
            bfr[kc][i] = *(const short8*)(W1hp +
                ((size_t)((8 * w + i) * 16 + kc) * 64 + lane) * 8);

    // ---- LDS-resident W1h (kc RKC..RKC+LKC-1) ----
    if (LKC > 0) {
        for (int c = tid; c < LKC * 2048; c += 256) {
            int j = c >> 11, r = c & 2047;
            int nt = r >> 6, ln = r & 63;
            *(short8*)&Wl[(size_t)c * 8] =
                *(const short8*)(W1hp + ((size_t)(nt * 16 + RKC + j) * 64 + ln) * 8);
        }
    }

    // ---- h^1 = tanh(xp[0] + b1) -> Hb[0] (each wave covers its 128 cols) ----
#pragma unroll
    for (int i = 0; i < 8; ++i) {
        Pack4 xv; xv.u = xq[xpidx(0 * 16 + rg, w, i, lane)];
#pragma unroll
        for (int r = 0; r < 4; ++r)
            Hb[(q * 4 + r) * HROW + (8 * w + i) * 16 + m] =
                f2bf(fast_tanh(bf2f(xv.h[r]) + b1));
    }
    __syncthreads();

    int p = 0;
#pragma unroll 1
    for (int t = 1; t < T_STEPS; ++t) {
        // xp[t] prefetch: 8 coalesced b64 loads
        Pack4 xv[8];
#pragma unroll
        for (int i = 0; i < 8; ++i)
            xv[i].u = xq[xpidx(t * 16 + rg, w, i, lane)];

        // first streamed kc issued up-front (covered by reg/LDS MFMAs)
        short8 sb[8];
        if (SKC0 < 16) {
#pragma unroll
            for (int i = 0; i < 8; ++i)
                sb[i] = *(const short8*)(W1hp +
                    ((size_t)((8 * w + i) * 16 + SKC0) * 64 + lane) * 8);
        }

        floatx4 acc[8];
#pragma unroll
        for (int i = 0; i < 8; ++i) acc[i] = (floatx4){0.f, 0.f, 0.f, 0.f};

        // register kcs
#pragma unroll
        for (int kc = 0; kc < RKC; ++kc) {
            short8 a = *(const short8*)&Hb[p * HBUF + m * HROW + kc * 32 + q * 8];
#pragma unroll
            for (int i = 0; i < 8; ++i)
                acc[i] = __builtin_amdgcn_mfma_f32_16x16x32_bf16(a, bfr[kc][i], acc[i], 0, 0, 0);
        }
        // LDS kcs
#pragma unroll
        for (int j = 0; j < LKC; ++j) {
            short8 a = *(const short8*)&Hb[p * HBUF + m * HROW + (RKC + j) * 32 + q * 8];
#pragma unroll
            for (int i = 0; i < 8; ++i) {
                short8 b = *(const short8*)&Wl[((size_t)(j * 32 + 8 * w + i) * 64 + lane) * 8];
                acc[i] = __builtin_amdgcn_mfma_f32_16x16x32_bf16(a, b, acc[i], 0, 0, 0);
            }
        }
        // streamed kcs: consume sb (MFMA reads old values), then reload for s+1
#pragma unroll
        for (int s = SKC0; s < 16; ++s) {
            short8 a = *(const short8*)&Hb[p * HBUF + m * HROW + s * 32 + q * 8];
#pragma unroll
            for (int i = 0; i < 8; ++i)
                acc[i] = __builtin_amdgcn_mfma_f32_16x16x32_bf16(a, sb[i], acc[i], 0, 0, 0);
            if (s + 1 < 16) {
#pragma unroll
                for (int i = 0; i < 8; ++i)
                    sb[i] = *(const short8*)(W1hp +
                        ((size_t)((8 * w + i) * 16 + s + 1) * 64 + lane) * 8);
            }
        }

        // epilogue: h^{t+1} -> other buffer (conflict-free scatter)
        unsigned short* hd = &Hb[(1 - p) * HBUF];
#pragma unroll
        for (int i = 0; i < 8; ++i)
#pragma unroll
            for (int r = 0; r < 4; ++r) {
                float v = acc[i][r] + bf2f(xv[i].h[r]) + b1;
                hd[(q * 4 + r) * HROW + (8 * w + i) * 16 + m] = f2bf(fast_tanh(v));
            }
        __syncthreads();
        p ^= 1;
    }

    // ---- tail: out[:, 32w..32w+32) = h^512 @ W2 + b2 (packed W2) ----
    const float b2 = b2p[0];
    floatx4 ao[2];
#pragma unroll
    for (int u = 0; u < 2; ++u) ao[u] = (floatx4){0.f, 0.f, 0.f, 0.f};
#pragma unroll
    for (int kc = 0; kc < 16; ++kc) {
        short8 a = *(const short8*)&Hb[p * HBUF + m * HROW + kc * 32 + q * 8];
#pragma unroll
        for (int u = 0; u < 2; ++u) {
            short8 b = *(const short8*)(W2p +
                ((size_t)((2 * w + u) * 16 + kc) * 64 + lane) * 8);
            ao[u] = __builtin_amdgcn_mfma_f32_16x16x32_bf16(a, b, ao[u], 0, 0, 0);
        }
    }
#pragma unroll
    for (int u = 0; u < 2; ++u)
#pragma unroll
        for (int r = 0; r < 4; ++r)
            out[(size_t)(rg * 16 + q * 4 + r) * DOUT + (2 * w + u) * 16 + m] = ao[u][r] + b2;
#undef HROW
#undef HBUF
}

// ---------------------------------------------------------------------------
extern "C" void kernel_launch(void* const* d_in, const int* in_sizes, int n_in,
                              void* d_out, int out_size, void* d_ws, size_t ws_size,
                              hipStream_t stream) {
    const float* xs  = (const float*)d_in[0];
    const float* W1x = (const float*)d_in[1];
    const float* W1h = (const float*)d_in[2];
    const float* b1  = (const float*)d_in[3];
    const float* W2  = (const float*)d_in[4];
    const float* b2  = (const float*)d_in[5];
    float* out = (float*)d_out;

    // ws (bf16 elems): xp2 | W1h packed | W1x packed | W2 packed
    unsigned short* xp2  = (unsigned short*)d_ws;
    unsigned short* w1hp = xp2 + (size_t)T_STEPS * BATCH * DH;     // 67,108,864
    unsigned short* w1xp = w1hp + (size_t)DH * DH;                 // +262,144
    unsigned short* w2p  = w1xp + (size_t)DIN * DH;                // +65,536

    pack_b_kernel<<<(DH * DH + 255) / 256, 256, 0, stream>>>(W1h, w1hp, DH, DH);
    pack_b_kernel<<<(DIN * DH + 255) / 256, 256, 0, stream>>>(W1x, w1xp, DIN, DH);
    pack_b_kernel<<<(DH * DOUT + 255) / 256, 256, 0, stream>>>(W2, w2p, DH, DOUT);
    xproj_kernel<<<(T_STEPS * BATCH) / 16, 256, 0, stream>>>(
        xs, w1xp, (unsigned long long*)xp2);

    // Big: Hb 33,024 B + 3 kc Wl 98,304 B = 131,328 B dynamic LDS (>64 KB
    // opt-in). Fallback: Hb only, stream 6 kc. Deterministic -> graph-safe.
    constexpr size_t SMEM_BIG   = (2 * 16 * 516 + 3 * 2048 * 8) * 2;  // 131328
    constexpr size_t SMEM_SMALL = 2 * 16 * 516 * 2;                   //  33024
    hipError_t e = hipFuncSetAttribute(
        reinterpret_cast<const void*>(&rnn_kernel<3>),
        hipFuncAttributeMaxDynamicSharedMemorySize, (int)SMEM_BIG);
    if (e == hipSuccess) {
        rnn_kernel<3><<<RGRP, 256, SMEM_BIG, stream>>>(
            (const unsigned long long*)xp2, w1hp, b1, w2p, b2, out);
    } else {
        rnn_kernel<0><<<RGRP, 256, SMEM_SMALL, stream>>>(
            (const unsigned long long*)xp2, w1hp, b1, w2p, b2, out);
    }
}